// Round 12
// baseline (558.350 us; speedup 1.0000x reference)
//
#include <hip/hip_runtime.h>
#include <math.h>

#define SS 1024
#define DD 64
#define BH 64

typedef __attribute__((ext_vector_type(4))) float fx4;
typedef __attribute__((ext_vector_type(8))) short sx8;
typedef __attribute__((ext_vector_type(4))) short sx4;

__device__ __forceinline__ unsigned short f2bf(float x) {
  unsigned u = __builtin_bit_cast(unsigned, x);
  u += 0x7fffu + ((u >> 16) & 1u);
  return (unsigned short)(u >> 16);
}
__device__ __forceinline__ float bf2f(unsigned short h) {
  return __builtin_bit_cast(float, ((unsigned)h) << 16);
}

// lgkm-only barrier (r9-r11, verified): in-loop boundaries order only LDS;
// vmcnt not drained (prefetch + W-stores stay in flight). rule #18 fences.
#define BAR_LGKM()                                          \
  do {                                                      \
    asm volatile("s_waitcnt lgkmcnt(0)" ::: "memory");      \
    __builtin_amdgcn_sched_barrier(0);                      \
    __builtin_amdgcn_s_barrier();                           \
    __builtin_amdgcn_sched_barrier(0);                      \
  } while (0)

// ---------------------------------------------------------------------------
// Round-12 = r11 frame (300 us, passed) restructured as TWO PASSES to kill
// the 268 MB tail W re-read/re-write (r10/r11 showed dur == hbm_bytes /
// 2.13 TB/s -> byte-bound):
//  PASS 1 (per tile: [BAR] stage K/RK [BAR] logits + shuffle/exp -> row-sum
//          in registers). No V staging, no W store, no PV, no LDS w-buffers.
//  wave-local 16-lane reduce -> rI (registers; no LDS, no barrier).
//  PASS 2 = r11 tile loop, but w = exp(val)*rI written ONCE (final, fp32)
//          and wA/wSk hold NORMALIZED bf16 w -> O = accO directly.
//  Tail: just the O store. No W readback, no rowInvLds, no tail barriers.
// Pass-1/pass-2 logits are bitwise identical (same staged bf16, same MFMA
// order), so W/O values are bit-identical to r11's (same two fp32 factors).
// Bytes: 638 -> ~360 MB. LDS layout/aliasing, prefetch, barriers = r11.
// ---------------------------------------------------------------------------
__global__ __launch_bounds__(256, 2) void k_fused(
    const float* __restrict__ q, const float* __restrict__ k,
    const float* __restrict__ v, const float* __restrict__ RK,
    const float* __restrict__ RV, float* __restrict__ W, float* __restrict__ O) {
  // XCD-contiguous remap: 512 blocks, XCD x -> bh in [8x,8x+8), all 8 pairs
  const int bid = (blockIdx.y << 3) | blockIdx.x;
  const int nb = ((bid & 7) << 6) | (bid >> 3);
  const int p = nb & 7, bh = nb >> 3;

  __shared__ __align__(16) char smem[81408];
  short* const sKh = (short*)smem;            // [64*72]   0..9216
  short* const sKl = (short*)(smem + 9216);   // [64*72]   ..18432
  short* const sRh = (short*)(smem + 18432);  // [128*72]  ..36864
  short* const vT  = (short*)(smem + 36864);  // [64*74]   ..46336
  short* const rvT = (short*)(smem + 46336);  // [64*138]  ..64000
  short* const wSk = (short*)(smem + 64000);  // [64*136]  ..81408
  short* const wA  = (short*)smem;            // [64*72] aliases sKh (dead after b2)

  const int t = threadIdx.x;
  const int lane = t & 63, mt = t >> 6, quad = lane >> 4, lc = lane & 15;

  // one-time: zero the never-valid wSk slots (wave-private rows; no barrier)
#pragma unroll
  for (int e = 0; e < 4; ++e) {
    const int rr = quad * 4 + e;
    const int rloc = mt * 16 + rr;
    const int du = 63 + lc - rr;         // [48,78]
    const int us0 = du & 15;
    const int A = (du >> 4) - mt;        // valid kk = nt + A, nt=0..3
#pragma unroll
    for (int kk = 0; kk < 8; ++kk) {
      if (kk < A || kk > A + 3) wSk[rloc * 136 + us0 + 16 * kk] = 0;
    }
  }

  // ---- one-tile-ahead prefetch registers (wave-private) -------------------
  float4 kpf[4], rkpf[8], vpf[4], rvpf[8];

  auto issueKRK = [&](const int j0, const int i0) {
#pragma unroll
    for (int i2 = 0; i2 < 4; ++i2) {
      const int idx = t + (i2 << 8);
      kpf[i2] = *(const float4*)(k + ((size_t)(bh * SS + j0 + (idx >> 4))) * DD + (idx & 15) * 4);
    }
    const int pLo = j0 - i0 - 63 + 512;
#pragma unroll
    for (int i2 = 0; i2 < 8; ++i2) {
      const int idx = t + (i2 << 8);
      int pp = pLo + (idx >> 4);
      pp = pp < 0 ? 0 : (pp > 512 ? 512 : pp);
      rkpf[i2] = *(const float4*)(RK + (size_t)pp * DD + (idx & 15) * 4);
    }
    __builtin_amdgcn_sched_barrier(0);  // pin issue here (r7: sunk without)
  };
  auto issueVRV = [&](const int j0, const int i0) {
#pragma unroll
    for (int i2 = 0; i2 < 4; ++i2) {
      const int idx = t + (i2 << 8);
      vpf[i2] = *(const float4*)(v + ((size_t)(bh * SS + j0 + (idx >> 4))) * DD + (idx & 15) * 4);
    }
    const int pLo = j0 - i0 - 63 + 512;
#pragma unroll
    for (int i2 = 0; i2 < 8; ++i2) {
      const int idx = t + (i2 << 8);
      int pp = pLo + (idx >> 4);
      pp = pp < 0 ? 0 : (pp > 512 ? 512 : pp);
      rvpf[i2] = *(const float4*)(RV + (size_t)pp * DD + (idx & 15) * 4);
    }
    __builtin_amdgcn_sched_barrier(0);
  };

  // convert prefetched K/RK regs -> LDS
  auto stageKRK = [&]() {
#pragma unroll
    for (int i2 = 0; i2 < 4; ++i2) {
      const int idx = t + (i2 << 8);
      const int row = idx >> 4, c4 = (idx & 15) * 4;
      const float xs[4] = {kpf[i2].x, kpf[i2].y, kpf[i2].z, kpf[i2].w};
      sx4 h, l;
#pragma unroll
      for (int e = 0; e < 4; ++e) {
        const unsigned short hb = f2bf(xs[e]);
        h[e] = (short)hb;
        l[e] = (short)f2bf(xs[e] - bf2f(hb));
      }
      *(sx4*)&sKh[row * 72 + c4] = h;
      *(sx4*)&sKl[row * 72 + c4] = l;
    }
#pragma unroll
    for (int i2 = 0; i2 < 8; ++i2) {
      const int idx = t + (i2 << 8);
      const int u = idx >> 4, c4 = (idx & 15) * 4;
      sx4 h;
      h[0] = (short)f2bf(rkpf[i2].x); h[1] = (short)f2bf(rkpf[i2].y);
      h[2] = (short)f2bf(rkpf[i2].z); h[3] = (short)f2bf(rkpf[i2].w);
      *(sx4*)&sRh[u * 72 + c4] = h;
    }
  };
  // convert prefetched V/RV regs -> LDS (pass 2 only)
  auto stageVRV = [&]() {
#pragma unroll
    for (int i2 = 0; i2 < 4; ++i2) {
      const int idx = t + (i2 << 8);
      const int jj = idx >> 4, d4 = (idx & 15) * 4;
      vT[(d4 + 0) * 74 + jj] = (short)f2bf(vpf[i2].x);
      vT[(d4 + 1) * 74 + jj] = (short)f2bf(vpf[i2].y);
      vT[(d4 + 2) * 74 + jj] = (short)f2bf(vpf[i2].z);
      vT[(d4 + 3) * 74 + jj] = (short)f2bf(vpf[i2].w);
    }
#pragma unroll
    for (int i2 = 0; i2 < 8; ++i2) {
      const int idx = t + (i2 << 8);
      const int u = idx >> 4, d4 = (idx & 15) * 4;
      rvT[(d4 + 0) * 138 + u] = (short)f2bf(rvpf[i2].x);
      rvT[(d4 + 1) * 138 + u] = (short)f2bf(rvpf[i2].y);
      rvT[(d4 + 2) * 138 + u] = (short)f2bf(rvpf[i2].z);
      rvT[(d4 + 3) * 138 + u] = (short)f2bf(rvpf[i2].w);
    }
  };

  // prologue: issue half-0 pass-1 tile-0 K/RK
  issueKRK(0, p << 6);

  for (int half = 0; half < 2; ++half) {
    const int it = half ? 15 - p : p;
    const int i0 = it << 6;

    // zero the fully-masked upper W columns (wave-per-row, contiguous)
    {
      float4 z; z.x = z.y = z.z = z.w = 0.f;
      for (int r = mt; r < 64; r += 4) {
        float* Wrow = W + ((size_t)(bh * SS + i0 + r)) * SS;
        for (int j = (it + 1) * 64 + lane * 4; j < SS; j += 256)
          *(float4*)(Wrow + j) = z;
      }
    }

    // Q fragments (hi/lo split) in registers for this stripe
    sx8 aQh[2], aQl[2];
    {
      const float* qrow = q + ((size_t)(bh * SS + i0 + mt * 16 + lc)) * DD;
#pragma unroll
      for (int ks = 0; ks < 2; ++ks) {
        const int koff = ks * 32 + quad * 8;
        const float4 x0 = *(const float4*)(qrow + koff);
        const float4 x1 = *(const float4*)(qrow + koff + 4);
        const float xs[8] = {x0.x, x0.y, x0.z, x0.w, x1.x, x1.y, x1.z, x1.w};
#pragma unroll
        for (int e = 0; e < 8; ++e) {
          const unsigned short hb = f2bf(xs[e]);
          aQh[ks][e] = (short)hb;
          aQl[ks][e] = (short)f2bf(xs[e] - bf2f(hb));
        }
      }
    }

    const fx4 zz = {0.f, 0.f, 0.f, 0.f};

    // shared logits-MFMA block (identical in both passes -> bitwise-equal val)
    auto logitsTile = [&](fx4* accS1, fx4* accS2) {
#pragma unroll
      for (int ks = 0; ks < 2; ++ks) {
        const int koff = ks * 32 + quad * 8;
#pragma unroll
        for (int nt = 0; nt < 4; ++nt) {
          const sx8 bKh = *(const sx8*)&sKh[(nt * 16 + lc) * 72 + koff];
          const sx8 bKl = *(const sx8*)&sKl[(nt * 16 + lc) * 72 + koff];
          accS1[nt] = __builtin_amdgcn_mfma_f32_16x16x32_bf16(aQh[ks], bKh, accS1[nt], 0, 0, 0);
          accS1[nt] = __builtin_amdgcn_mfma_f32_16x16x32_bf16(aQl[ks], bKh, accS1[nt], 0, 0, 0);
          accS1[nt] = __builtin_amdgcn_mfma_f32_16x16x32_bf16(aQh[ks], bKl, accS1[nt], 0, 0, 0);
        }
#pragma unroll
        for (int s = 0; s < 5; ++s) {
          const sx8 bR = *(const sx8*)&sRh[((3 - mt + s) * 16 + lc) * 72 + koff];
          accS2[s] = __builtin_amdgcn_mfma_f32_16x16x32_bf16(aQh[ks], bR, accS2[s], 0, 0, 0);
        }
      }
    };

    // ---------------- PASS 1: row sums only ------------------------------
    float sAcc[4] = {0.f, 0.f, 0.f, 0.f};
    for (int jt = 0; jt <= it; ++jt) {
      const int j0 = jt * 64;
      if (jt | half) BAR_LGKM();  // prev logits/PV LDS reads done
      stageKRK();
      if (jt < it) issueKRK(j0 + 64, i0);
      else { issueKRK(0, i0); issueVRV(0, i0); }  // pass-2 tile 0
      BAR_LGKM();  // staged K/RK visible

      fx4 accS1[4] = {zz, zz, zz, zz};
      fx4 accS2[5] = {zz, zz, zz, zz, zz};
      logitsTile(accS1, accS2);

      // sum epilogue (sync-free; registers only)
#pragma unroll
      for (int nt = 0; nt < 4; ++nt) {
#pragma unroll
        for (int e = 0; e < 4; ++e) {
          const int rr = quad * 4 + e;
          const int du = 63 + lc - rr;
          const int srcLane = (lane & 48) | (du & 15);
          const float g0 = __shfl(accS2[nt][e], srcLane, 64);
          const float g1 = __shfl(accS2[nt + 1][e], srcLane, 64);
          const float val = accS1[nt][e] + (du < 64 ? g0 : g1);
          const int col = j0 + nt * 16 + lc;
          if (col <= i0 + mt * 16 + rr) sAcc[e] += __expf(val);
        }
      }
    }
    // wave-local 16-lane reduce -> row inverses (registers; no LDS/barrier)
#pragma unroll
    for (int off = 1; off <= 8; off <<= 1) {
#pragma unroll
      for (int e = 0; e < 4; ++e) sAcc[e] += __shfl_xor(sAcc[e], off, 64);
    }
    float rI[4];
#pragma unroll
    for (int e = 0; e < 4; ++e) rI[e] = 1.f / sAcc[e];

    // ---------------- PASS 2: normalized W + O ---------------------------
    fx4 accO[4] = {zz, zz, zz, zz};
    for (int jt = 0; jt <= it; ++jt) {
      const int j0 = jt * 64;
      BAR_LGKM();  // pass-1 last (or prev tile's) LDS reads done
      stageKRK();
      stageVRV();
      if (jt < it) { issueKRK(j0 + 64, i0); issueVRV(j0 + 64, i0); }
      else if (half == 0) issueKRK(0, (15 - p) << 6);  // half-1 pass-1 tile 0
      BAR_LGKM();  // staged K/RK/vT/rvT visible

      fx4 accS1[4] = {zz, zz, zz, zz};
      fx4 accS2[5] = {zz, zz, zz, zz, zz};
      logitsTile(accS1, accS2);
      BAR_LGKM();  // logits reads done -> sKh region (wA alias) is free

      // sync-free back half: w = exp(val)*rI (FINAL), W store, wA/wSk, PV
#pragma unroll
      for (int nt = 0; nt < 4; ++nt) {
#pragma unroll
        for (int e = 0; e < 4; ++e) {
          const int rr = quad * 4 + e;
          const int du = 63 + lc - rr;
          const int srcLane = (lane & 48) | (du & 15);
          const float g0 = __shfl(accS2[nt][e], srcLane, 64);
          const float g1 = __shfl(accS2[nt + 1][e], srcLane, 64);
          const float val = accS1[nt][e] + (du < 64 ? g0 : g1);
          const int col = j0 + nt * 16 + lc;
          const int rowg = i0 + mt * 16 + rr;
          const float w = (col <= rowg) ? __expf(val) * rI[e] : 0.f;
          W[((size_t)(bh * SS + rowg)) * SS + col] = w;
          const unsigned short h = f2bf(w);
          wA[(mt * 16 + rr) * 72 + nt * 16 + lc] = (short)h;
          wSk[(mt * 16 + rr) * 136 + du + 16 * (nt - mt)] = (short)h;
        }
      }
      // wave-local ordering: own wA/wSk writes complete before own PV reads
      asm volatile("s_waitcnt lgkmcnt(0)" ::: "memory");
      __builtin_amdgcn_sched_barrier(0);

      // O += w @ v   (K = 64 over j)
#pragma unroll
      for (int ks = 0; ks < 2; ++ks) {
        const int koff = ks * 32 + quad * 8;
        const sx8 aW = *(const sx8*)&wA[(mt * 16 + lc) * 72 + koff];
#pragma unroll
        for (int nt = 0; nt < 4; ++nt) {
          const sx8 bV = *(const sx8*)&vT[(nt * 16 + lc) * 74 + koff];
          accO[nt] = __builtin_amdgcn_mfma_f32_16x16x32_bf16(aW, bV, accO[nt], 0, 0, 0);
        }
      }
      // O += wskew @ RVstaged   (K = 128 over u)
#pragma unroll
      for (int ks = 0; ks < 4; ++ks) {
        const int koff = ks * 32 + quad * 8;
        const sx8 aS = *(const sx8*)&wSk[(mt * 16 + lc) * 136 + koff];
#pragma unroll
        for (int nt = 0; nt < 4; ++nt) {
          const sx8 bR = *(const sx8*)&rvT[(nt * 16 + lc) * 138 + koff];
          accO[nt] = __builtin_amdgcn_mfma_f32_16x16x32_bf16(aS, bR, accO[nt], 0, 0, 0);
        }
      }
    }

    // tail: O is already normalized (w was) -> direct store, no LDS, no sync
#pragma unroll
    for (int nt = 0; nt < 4; ++nt) {
#pragma unroll
      for (int e = 0; e < 4; ++e) {
        O[((size_t)(bh * SS + i0 + mt * 16 + quad * 4 + e)) * DD + nt * 16 + lc] =
            accO[nt][e];
      }
    }
  }
}

extern "C" void kernel_launch(void* const* d_in, const int* in_sizes, int n_in,
                              void* d_out, int out_size, void* d_ws, size_t ws_size,
                              hipStream_t stream) {
  const float* q = (const float*)d_in[0];
  const float* k = (const float*)d_in[1];
  const float* v = (const float*)d_in[2];
  const float* RK = (const float*)d_in[3];  // (1025,64); causal => rows 0..512
  const float* RV = (const float*)d_in[4];

  float* O = (float*)d_out;                         // (B,H,S,D)
  float* W = (float*)d_out + (size_t)BH * SS * DD;  // (B,H,S,S)

  k_fused<<<dim3(8, BH), 256, 0, stream>>>(q, k, v, RK, RV, W, O);
}